// Round 1
// baseline (639.615 us; speedup 1.0000x reference)
//
#include <hip/hip_runtime.h>

// MUTAN fused bilinear (low-rank Tucker) + ReLU + LayerNorm, MI355X gfx950.
// Round 1: bf16 MFMA path with pre-convert/pre-transpose into d_ws (80 MB),
// m97-style 128x128 tile, linear LDS, 2-barrier K-loop. f32 fallback if ws small.

typedef unsigned short u16;
typedef __attribute__((ext_vector_type(8))) short bf16x8;   // 8 bf16 = 4 VGPRs
typedef __attribute__((ext_vector_type(4))) float f32x4;    // MFMA C/D

constexpr int Bq = 4096;   // batch
constexpr int D  = 1024;   // contraction dim
constexpr int Zq = 1024;   // output dim
constexpr int Rk = 16;     // rank
constexpr int BM = 128, BN = 128, BK = 64;

__device__ __forceinline__ u16 f2b(float f) {
  union { float f; unsigned u; } c; c.f = f;
  unsigned r = (c.u + 0x7FFFu + ((c.u >> 16) & 1u)) >> 16;  // RNE
  return (u16)r;
}

// ---- prep: f32 -> bf16 (4M elems, exact grid) ----
__global__ __launch_bounds__(256) void cvt_bf16(const float* __restrict__ s,
                                                u16* __restrict__ d) {
  const int i = blockIdx.x * 256 + threadIdx.x;   // 0 .. 1048575 float4s
  const float4 f = ((const float4*)s)[i];
  union { u16 h[4]; uint2 u; } o;
  o.h[0] = f2b(f.x); o.h[1] = f2b(f.y); o.h[2] = f2b(f.z); o.h[3] = f2b(f.w);
  ((uint2*)d)[i] = o.u;
}

// ---- prep: U [r][k][j] f32 -> Ut [r][j][k] bf16 (32x32 LDS transpose) ----
__global__ __launch_bounds__(256) void transpose_cvt(const float* __restrict__ src,
                                                     u16* __restrict__ dst) {
  __shared__ float t[32][33];
  const int r = blockIdx.z;
  const int j0 = blockIdx.x * 32, k0 = blockIdx.y * 32;
  const int tx = threadIdx.x, ty = threadIdx.y;          // 32 x 8
  const float* s = src + (size_t)r * (D * Zq);
  u16* d = dst + (size_t)r * (D * Zq);
  #pragma unroll
  for (int i = 0; i < 4; ++i)
    t[ty + i * 8][tx] = s[(size_t)(k0 + ty + i * 8) * Zq + j0 + tx];
  __syncthreads();
  #pragma unroll
  for (int i = 0; i < 4; ++i)
    d[(size_t)(j0 + ty + i * 8) * D + k0 + tx] = f2b(t[tx][ty + i * 8]);
}

// ---- main: fused bilinear, bf16 MFMA ----
// grid (Bq/BM=32, Zq/BN=8), 512 threads = 8 waves in 2(m) x 4(n) grid,
// wave tile 64x32 = 4x2 fragments of 16x16.
__global__ __launch_bounds__(512, 2) void fused_bilinear(
    const u16* __restrict__ hdb, const u16* __restrict__ hpb,
    const u16* __restrict__ Ut, const u16* __restrict__ Vt,
    float* __restrict__ out)
{
  __shared__ __align__(16) u16 sA[BM * BK];
  __shared__ __align__(16) u16 sB[BM * BK];
  __shared__ __align__(16) u16 sU[BN * BK];
  __shared__ __align__(16) u16 sV[BN * BK];

  const int tid  = threadIdx.x;
  const int lane = tid & 63;
  const int wv   = tid >> 6;
  const int wm   = wv >> 2;               // 0..1
  const int wn   = wv & 3;                // 0..3
  const int lm   = lane & 15;             // A row / B col within fragment
  const int lk   = (lane >> 4) << 3;      // k offset: 0,8,16,24

  const int brow = blockIdx.x * BM;
  const int jcol = blockIdx.y * BN;

  const u16* hdp = hdb + (size_t)brow * D;
  const u16* hpp = hpb + (size_t)brow * D;

  f32x4 acc[4][2];
  #pragma unroll
  for (int mf = 0; mf < 4; ++mf)
    #pragma unroll
    for (int nf = 0; nf < 2; ++nf)
      acc[mf][nf] = (f32x4){0.f, 0.f, 0.f, 0.f};

  for (int r = 0; r < Rk; ++r) {
    const u16* up = Ut + (size_t)r * (D * Zq) + (size_t)jcol * D;
    const u16* vp = Vt + (size_t)r * (D * Zq) + (size_t)jcol * D;

    f32x4 au[4][2], av[4][2];
    #pragma unroll
    for (int mf = 0; mf < 4; ++mf)
      #pragma unroll
      for (int nf = 0; nf < 2; ++nf) {
        au[mf][nf] = (f32x4){0.f, 0.f, 0.f, 0.f};
        av[mf][nf] = (f32x4){0.f, 0.f, 0.f, 0.f};
      }

    for (int kt = 0; kt < D / BK; ++kt) {
      __syncthreads();                    // protect LDS from previous reads
      const int kb = kt * BK;
      // stage 4 tiles of [128 rows][64 cols] bf16; 1024 16B-chunks each,
      // 512 threads -> 2 chunks/thread/tile; coalesced 16B loads.
      #pragma unroll
      for (int i = 0; i < 2; ++i) {
        const int c   = tid + i * 512;
        const int row = c >> 3;
        const int sl  = (c & 7) << 3;     // element offset within row
        const int lo  = row * BK + sl;
        const size_t go = (size_t)row * D + kb + sl;
        *(uint4*)&sA[lo] = *(const uint4*)&hdp[go];
        *(uint4*)&sB[lo] = *(const uint4*)&hpp[go];
        *(uint4*)&sU[lo] = *(const uint4*)&up[go];
        *(uint4*)&sV[lo] = *(const uint4*)&vp[go];
      }
      __syncthreads();

      #pragma unroll
      for (int kk = 0; kk < 2; ++kk) {
        const int ko = kk * 32 + lk;
        bf16x8 a[4], b[4], bu[2], bv[2];
        #pragma unroll
        for (int mf = 0; mf < 4; ++mf) {
          const int rw = (wm * 64 + mf * 16 + lm) * BK + ko;
          a[mf] = *(const bf16x8*)&sA[rw];
          b[mf] = *(const bf16x8*)&sB[rw];
        }
        #pragma unroll
        for (int nf = 0; nf < 2; ++nf) {
          const int rw = (wn * 32 + nf * 16 + lm) * BK + ko;
          bu[nf] = *(const bf16x8*)&sU[rw];
          bv[nf] = *(const bf16x8*)&sV[rw];
        }
        #pragma unroll
        for (int mf = 0; mf < 4; ++mf)
          #pragma unroll
          for (int nf = 0; nf < 2; ++nf) {
            au[mf][nf] = __builtin_amdgcn_mfma_f32_16x16x32_bf16(
                a[mf], bu[nf], au[mf][nf], 0, 0, 0);
            av[mf][nf] = __builtin_amdgcn_mfma_f32_16x16x32_bf16(
                b[mf], bv[nf], av[mf][nf], 0, 0, 0);
          }
      }
    }
    // combine rank r: Hadamard in fragment space (identical C/D layout)
    #pragma unroll
    for (int mf = 0; mf < 4; ++mf)
      #pragma unroll
      for (int nf = 0; nf < 2; ++nf)
        #pragma unroll
        for (int i = 0; i < 4; ++i)
          acc[mf][nf][i] += au[mf][nf][i] * av[mf][nf][i];
  }

  // epilogue: ReLU + store f32. C/D: col = lane&15, row = 4*(lane>>4)+i.
  #pragma unroll
  for (int mf = 0; mf < 4; ++mf)
    #pragma unroll
    for (int nf = 0; nf < 2; ++nf) {
      const int gr = brow + wm * 64 + mf * 16 + ((lane >> 4) << 2);
      const int gc = jcol + wn * 32 + nf * 16 + lm;
      #pragma unroll
      for (int i = 0; i < 4; ++i)
        out[(size_t)(gr + i) * Zq + gc] = fmaxf(acc[mf][nf][i], 0.f);
    }
}

// ---- LayerNorm over rows of d_out, in place. Matches jnp.var (ddof=0). ----
__global__ __launch_bounds__(256) void ln_rows(float* __restrict__ out,
    const float* __restrict__ gamma, const float* __restrict__ beta)
{
  const int row = blockIdx.x;
  float* p = out + (size_t)row * Zq;
  const int t = threadIdx.x;
  float4 v = ((const float4*)p)[t];
  float s = v.x + v.y + v.z + v.w;
  float q = v.x * v.x + v.y * v.y + v.z * v.z + v.w * v.w;
  #pragma unroll
  for (int o = 32; o > 0; o >>= 1) {
    s += __shfl_xor(s, o);
    q += __shfl_xor(q, o);
  }
  __shared__ float ss[4], sq[4];
  if ((t & 63) == 0) { ss[t >> 6] = s; sq[t >> 6] = q; }
  __syncthreads();
  s = ss[0] + ss[1] + ss[2] + ss[3];
  q = sq[0] + sq[1] + sq[2] + sq[3];
  const float mean = s * (1.f / Zq);
  float var = q * (1.f / Zq) - mean * mean;
  var = fmaxf(var, 0.f);
  const float rstd = rsqrtf(var + 1e-5f);
  const float4 g  = ((const float4*)gamma)[t];
  const float4 bb = ((const float4*)beta)[t];
  v.x = (v.x - mean) * rstd * g.x + bb.x;
  v.y = (v.y - mean) * rstd * g.y + bb.y;
  v.z = (v.z - mean) * rstd * g.z + bb.z;
  v.w = (v.w - mean) * rstd * g.w + bb.w;
  ((float4*)p)[t] = v;
}

// ---- fallback (only if ws_size < 80 MB): plain f32, correct but slow ----
__global__ __launch_bounds__(256) void fallback_bilinear(
    const float* __restrict__ hd, const float* __restrict__ hp,
    const float* __restrict__ U, const float* __restrict__ V,
    float* __restrict__ out)
{
  const int j  = blockIdx.x * 256 + threadIdx.x;  // grid.x = 4
  const int b0 = blockIdx.y * 8;                  // grid.y = 512
  float acc[8] = {0.f, 0.f, 0.f, 0.f, 0.f, 0.f, 0.f, 0.f};
  for (int r = 0; r < Rk; ++r) {
    float u[8] = {0.f}, v[8] = {0.f};
    const float* Up = U + (size_t)r * (D * Zq) + j;
    const float* Vp = V + (size_t)r * (D * Zq) + j;
    for (int k = 0; k < D; ++k) {
      const float uu = Up[(size_t)k * Zq];
      const float vv = Vp[(size_t)k * Zq];
      #pragma unroll
      for (int bi = 0; bi < 8; ++bi) {
        u[bi] = fmaf(hd[(size_t)(b0 + bi) * D + k], uu, u[bi]);
        v[bi] = fmaf(hp[(size_t)(b0 + bi) * D + k], vv, v[bi]);
      }
    }
    #pragma unroll
    for (int bi = 0; bi < 8; ++bi) acc[bi] += u[bi] * v[bi];
  }
  #pragma unroll
  for (int bi = 0; bi < 8; ++bi)
    out[(size_t)(b0 + bi) * Zq + j] = fmaxf(acc[bi], 0.f);
}

extern "C" void kernel_launch(void* const* d_in, const int* in_sizes, int n_in,
                              void* d_out, int out_size, void* d_ws, size_t ws_size,
                              hipStream_t stream) {
  const float* hd    = (const float*)d_in[0];   // [4096][1024]
  const float* hp    = (const float*)d_in[1];   // [4096][1024]
  const float* U     = (const float*)d_in[2];   // [16][1024][1024]
  const float* V     = (const float*)d_in[3];   // [16][1024][1024]
  const float* gamma = (const float*)d_in[4];   // [1024]
  const float* beta  = (const float*)d_in[5];   // [1024]
  float* out = (float*)d_out;                   // [4096][1024] f32

  const size_t need = 80ull << 20;  // hd,hp bf16 (16MB) + Ut,Vt bf16 (64MB)
  if (ws_size >= need) {
    u16* hdb = (u16*)d_ws;                  // 4096*1024
    u16* hpb = hdb + (size_t)Bq * D;
    u16* Utb = hpb + (size_t)Bq * D;        // 16*1024*1024, [r][j][k]
    u16* Vtb = Utb + (size_t)Rk * D * Zq;

    cvt_bf16<<<4096, 256, 0, stream>>>(hd, hdb);
    cvt_bf16<<<4096, 256, 0, stream>>>(hp, hpb);
    transpose_cvt<<<dim3(32, 32, 16), dim3(32, 8), 0, stream>>>(U, Utb);
    transpose_cvt<<<dim3(32, 32, 16), dim3(32, 8), 0, stream>>>(V, Vtb);
    fused_bilinear<<<dim3(Bq / BM, Zq / BN), 512, 0, stream>>>(hdb, hpb, Utb, Vtb, out);
  } else {
    fallback_bilinear<<<dim3(Zq / 256, Bq / 8), 256, 0, stream>>>(hd, hp, U, V, out);
  }
  ln_rows<<<Bq, 256, 0, stream>>>(out, gamma, beta);
}

// Round 2
// 438.389 us; speedup vs baseline: 1.4590x; 1.4590x over previous
//
#include <hip/hip_runtime.h>

// MUTAN fused bilinear (low-rank Tucker) + ReLU + LayerNorm, MI355X gfx950.
// Round 2: global_load_lds(16B) staging + XOR bank-conflict swizzle
// (inverse-swizzled global source, linear LDS dest, swizzled ds_read).

typedef unsigned short u16;
typedef __attribute__((ext_vector_type(8))) short bf16x8;   // 8 bf16 = 4 VGPRs
typedef __attribute__((ext_vector_type(4))) float f32x4;    // MFMA C/D

constexpr int Bq = 4096;   // batch
constexpr int D  = 1024;   // contraction dim
constexpr int Zq = 1024;   // output dim
constexpr int Rk = 16;     // rank
constexpr int BM = 128, BN = 128, BK = 64;

typedef const __attribute__((address_space(1))) void* gas_t;
typedef __attribute__((address_space(3))) void* las_t;

__device__ __forceinline__ u16 f2b(float f) {
  union { float f; unsigned u; } c; c.f = f;
  unsigned r = (c.u + 0x7FFFu + ((c.u >> 16) & 1u)) >> 16;  // RNE
  return (u16)r;
}

// ---- prep: f32 -> bf16 (4M elems, exact grid) ----
__global__ __launch_bounds__(256) void cvt_bf16(const float* __restrict__ s,
                                                u16* __restrict__ d) {
  const int i = blockIdx.x * 256 + threadIdx.x;
  const float4 f = ((const float4*)s)[i];
  union { u16 h[4]; uint2 u; } o;
  o.h[0] = f2b(f.x); o.h[1] = f2b(f.y); o.h[2] = f2b(f.z); o.h[3] = f2b(f.w);
  ((uint2*)d)[i] = o.u;
}

// ---- prep: U [r][k][j] f32 -> Ut [r][j][k] bf16 (32x32 LDS transpose) ----
__global__ __launch_bounds__(256) void transpose_cvt(const float* __restrict__ src,
                                                     u16* __restrict__ dst) {
  __shared__ float t[32][33];
  const int r = blockIdx.z;
  const int j0 = blockIdx.x * 32, k0 = blockIdx.y * 32;
  const int tx = threadIdx.x, ty = threadIdx.y;          // 32 x 8
  const float* s = src + (size_t)r * (D * Zq);
  u16* d = dst + (size_t)r * (D * Zq);
  #pragma unroll
  for (int i = 0; i < 4; ++i)
    t[ty + i * 8][tx] = s[(size_t)(k0 + ty + i * 8) * Zq + j0 + tx];
  __syncthreads();
  #pragma unroll
  for (int i = 0; i < 4; ++i)
    d[(size_t)(j0 + ty + i * 8) * D + k0 + tx] = f2b(t[tx][ty + i * 8]);
}

// swizzled LDS fragment read: tile is [rows][BK] bf16 linear in LDS, but the
// data was staged with source chunk index XOR'd by (row&7); undo on read.
__device__ __forceinline__ bf16x8 lds_read_swz(const u16* base, int row, int ko) {
  int byte = (row * BK + ko) * 2;
  byte ^= (row & 7) << 4;
  return *(const bf16x8*)((const char*)base + byte);
}

// ---- main: fused bilinear, bf16 MFMA ----
// grid (Bq/BM=32, Zq/BN=8) = 256 blocks (1/CU), 512 threads = 8 waves (2m x 4n),
// wave tile 64x32 = 4x2 fragments of 16x16, K-step 64.
__global__ __launch_bounds__(512, 2) void fused_bilinear(
    const u16* __restrict__ hdb, const u16* __restrict__ hpb,
    const u16* __restrict__ Ut, const u16* __restrict__ Vt,
    float* __restrict__ out)
{
  __shared__ __align__(16) u16 sA[BM * BK];
  __shared__ __align__(16) u16 sB[BM * BK];
  __shared__ __align__(16) u16 sU[BN * BK];
  __shared__ __align__(16) u16 sV[BN * BK];

  const int tid  = threadIdx.x;
  const int lane = tid & 63;
  const int wv   = tid >> 6;
  const int wm   = wv >> 2;               // 0..1
  const int wn   = wv & 3;                // 0..3
  const int lm   = lane & 15;             // fragment row/col
  const int lk   = (lane >> 4) << 3;      // k offset: 0,8,16,24

  const int brow = blockIdx.x * BM;
  const int jcol = blockIdx.y * BN;

  const u16* hdp = hdb + (size_t)brow * D;
  const u16* hpp = hpb + (size_t)brow * D;

  // staging geometry: each tile = 1024 chunks of 16B; wave w stages chunks
  // [ (w*2+i)*64 + lane ] for i=0,1 -> LDS base (w*2+i)*1024 bytes, linear.
  // Global source chunk within the row is XOR-swizzled: cs = c ^ (row&7).
  const int cl0 = wv * 128 + lane;        // i=0 chunk linear index
  const int row0 = cl0 >> 3,  c0 = cl0 & 7;
  const int cl1 = cl0 + 64;               // i=1
  const int row1 = cl1 >> 3,  c1 = cl1 & 7;
  const int src0 = row0 * D + ((c0 ^ (row0 & 7)) << 3);  // element offset (pre-kb)
  const int src1 = row1 * D + ((c1 ^ (row1 & 7)) << 3);
  u16* ldsA0 = &sA[wv * 1024];  u16* ldsA1 = ldsA0 + 512;   // 512 elems = 1KB
  u16* ldsB0 = &sB[wv * 1024];  u16* ldsB1 = ldsB0 + 512;
  u16* ldsU0 = &sU[wv * 1024];  u16* ldsU1 = ldsU0 + 512;
  u16* ldsV0 = &sV[wv * 1024];  u16* ldsV1 = ldsV0 + 512;

  f32x4 acc[4][2];
  #pragma unroll
  for (int mf = 0; mf < 4; ++mf)
    #pragma unroll
    for (int nf = 0; nf < 2; ++nf)
      acc[mf][nf] = (f32x4){0.f, 0.f, 0.f, 0.f};

  for (int r = 0; r < Rk; ++r) {
    const u16* up = Ut + (size_t)r * (D * Zq) + (size_t)jcol * D;
    const u16* vp = Vt + (size_t)r * (D * Zq) + (size_t)jcol * D;

    f32x4 au[4][2], av[4][2];
    #pragma unroll
    for (int mf = 0; mf < 4; ++mf)
      #pragma unroll
      for (int nf = 0; nf < 2; ++nf) {
        au[mf][nf] = (f32x4){0.f, 0.f, 0.f, 0.f};
        av[mf][nf] = (f32x4){0.f, 0.f, 0.f, 0.f};
      }

    for (int kt = 0; kt < D / BK; ++kt) {
      __syncthreads();                    // previous tile's reads done
      const int kb = kt * BK;
      // async global -> LDS, 16B/lane, linear LDS dest, swizzled source
      __builtin_amdgcn_global_load_lds((gas_t)(hdp + src0 + kb), (las_t)ldsA0, 16, 0, 0);
      __builtin_amdgcn_global_load_lds((gas_t)(hdp + src1 + kb), (las_t)ldsA1, 16, 0, 0);
      __builtin_amdgcn_global_load_lds((gas_t)(hpp + src0 + kb), (las_t)ldsB0, 16, 0, 0);
      __builtin_amdgcn_global_load_lds((gas_t)(hpp + src1 + kb), (las_t)ldsB1, 16, 0, 0);
      __builtin_amdgcn_global_load_lds((gas_t)(up  + src0 + kb), (las_t)ldsU0, 16, 0, 0);
      __builtin_amdgcn_global_load_lds((gas_t)(up  + src1 + kb), (las_t)ldsU1, 16, 0, 0);
      __builtin_amdgcn_global_load_lds((gas_t)(vp  + src0 + kb), (las_t)ldsV0, 16, 0, 0);
      __builtin_amdgcn_global_load_lds((gas_t)(vp  + src1 + kb), (las_t)ldsV1, 16, 0, 0);
      __syncthreads();                    // drains vmcnt before barrier

      #pragma unroll
      for (int kk = 0; kk < 2; ++kk) {
        const int ko = kk * 32 + lk;
        bf16x8 a[4], b[4], bu[2], bv[2];
        #pragma unroll
        for (int mf = 0; mf < 4; ++mf) {
          const int rw = wm * 64 + mf * 16 + lm;
          a[mf] = lds_read_swz(sA, rw, ko);
          b[mf] = lds_read_swz(sB, rw, ko);
        }
        #pragma unroll
        for (int nf = 0; nf < 2; ++nf) {
          const int rw = wn * 32 + nf * 16 + lm;
          bu[nf] = lds_read_swz(sU, rw, ko);
          bv[nf] = lds_read_swz(sV, rw, ko);
        }
        #pragma unroll
        for (int mf = 0; mf < 4; ++mf)
          #pragma unroll
          for (int nf = 0; nf < 2; ++nf) {
            au[mf][nf] = __builtin_amdgcn_mfma_f32_16x16x32_bf16(
                a[mf], bu[nf], au[mf][nf], 0, 0, 0);
            av[mf][nf] = __builtin_amdgcn_mfma_f32_16x16x32_bf16(
                b[mf], bv[nf], av[mf][nf], 0, 0, 0);
          }
      }
    }
    // combine rank r: Hadamard in fragment space (identical C/D layout)
    #pragma unroll
    for (int mf = 0; mf < 4; ++mf)
      #pragma unroll
      for (int nf = 0; nf < 2; ++nf)
        #pragma unroll
        for (int i = 0; i < 4; ++i)
          acc[mf][nf][i] += au[mf][nf][i] * av[mf][nf][i];
  }

  // epilogue: ReLU + store f32. C/D: col = lane&15, row = 4*(lane>>4)+i.
  #pragma unroll
  for (int mf = 0; mf < 4; ++mf)
    #pragma unroll
    for (int nf = 0; nf < 2; ++nf) {
      const int gr = brow + wm * 64 + mf * 16 + ((lane >> 4) << 2);
      const int gc = jcol + wn * 32 + nf * 16 + lm;
      #pragma unroll
      for (int i = 0; i < 4; ++i)
        out[(size_t)(gr + i) * Zq + gc] = fmaxf(acc[mf][nf][i], 0.f);
    }
}

// ---- LayerNorm over rows of d_out, in place. Matches jnp.var (ddof=0). ----
__global__ __launch_bounds__(256) void ln_rows(float* __restrict__ out,
    const float* __restrict__ gamma, const float* __restrict__ beta)
{
  const int row = blockIdx.x;
  float* p = out + (size_t)row * Zq;
  const int t = threadIdx.x;
  float4 v = ((const float4*)p)[t];
  float s = v.x + v.y + v.z + v.w;
  float q = v.x * v.x + v.y * v.y + v.z * v.z + v.w * v.w;
  #pragma unroll
  for (int o = 32; o > 0; o >>= 1) {
    s += __shfl_xor(s, o);
    q += __shfl_xor(q, o);
  }
  __shared__ float ss[4], sq[4];
  if ((t & 63) == 0) { ss[t >> 6] = s; sq[t >> 6] = q; }
  __syncthreads();
  s = ss[0] + ss[1] + ss[2] + ss[3];
  q = sq[0] + sq[1] + sq[2] + sq[3];
  const float mean = s * (1.f / Zq);
  float var = q * (1.f / Zq) - mean * mean;
  var = fmaxf(var, 0.f);
  const float rstd = rsqrtf(var + 1e-5f);
  const float4 g  = ((const float4*)gamma)[t];
  const float4 bb = ((const float4*)beta)[t];
  v.x = (v.x - mean) * rstd * g.x + bb.x;
  v.y = (v.y - mean) * rstd * g.y + bb.y;
  v.z = (v.z - mean) * rstd * g.z + bb.z;
  v.w = (v.w - mean) * rstd * g.w + bb.w;
  ((float4*)p)[t] = v;
}

// ---- fallback (only if ws_size < 80 MB): plain f32, correct but slow ----
__global__ __launch_bounds__(256) void fallback_bilinear(
    const float* __restrict__ hd, const float* __restrict__ hp,
    const float* __restrict__ U, const float* __restrict__ V,
    float* __restrict__ out)
{
  const int j  = blockIdx.x * 256 + threadIdx.x;
  const int b0 = blockIdx.y * 8;
  float acc[8] = {0.f, 0.f, 0.f, 0.f, 0.f, 0.f, 0.f, 0.f};
  for (int r = 0; r < Rk; ++r) {
    float u[8] = {0.f}, v[8] = {0.f};
    const float* Up = U + (size_t)r * (D * Zq) + j;
    const float* Vp = V + (size_t)r * (D * Zq) + j;
    for (int k = 0; k < D; ++k) {
      const float uu = Up[(size_t)k * Zq];
      const float vv = Vp[(size_t)k * Zq];
      #pragma unroll
      for (int bi = 0; bi < 8; ++bi) {
        u[bi] = fmaf(hd[(size_t)(b0 + bi) * D + k], uu, u[bi]);
        v[bi] = fmaf(hp[(size_t)(b0 + bi) * D + k], vv, v[bi]);
      }
    }
    #pragma unroll
    for (int bi = 0; bi < 8; ++bi) acc[bi] += u[bi] * v[bi];
  }
  #pragma unroll
  for (int bi = 0; bi < 8; ++bi)
    out[(size_t)(b0 + bi) * Zq + j] = fmaxf(acc[bi], 0.f);
}

extern "C" void kernel_launch(void* const* d_in, const int* in_sizes, int n_in,
                              void* d_out, int out_size, void* d_ws, size_t ws_size,
                              hipStream_t stream) {
  const float* hd    = (const float*)d_in[0];   // [4096][1024]
  const float* hp    = (const float*)d_in[1];   // [4096][1024]
  const float* U     = (const float*)d_in[2];   // [16][1024][1024]
  const float* V     = (const float*)d_in[3];   // [16][1024][1024]
  const float* gamma = (const float*)d_in[4];   // [1024]
  const float* beta  = (const float*)d_in[5];   // [1024]
  float* out = (float*)d_out;                   // [4096][1024] f32

  const size_t need = 80ull << 20;  // hd,hp bf16 (16MB) + Ut,Vt bf16 (64MB)
  if (ws_size >= need) {
    u16* hdb = (u16*)d_ws;                  // 4096*1024
    u16* hpb = hdb + (size_t)Bq * D;
    u16* Utb = hpb + (size_t)Bq * D;        // 16*1024*1024, [r][j][k]
    u16* Vtb = Utb + (size_t)Rk * D * Zq;

    cvt_bf16<<<4096, 256, 0, stream>>>(hd, hdb);
    cvt_bf16<<<4096, 256, 0, stream>>>(hp, hpb);
    transpose_cvt<<<dim3(32, 32, 16), dim3(32, 8), 0, stream>>>(U, Utb);
    transpose_cvt<<<dim3(32, 32, 16), dim3(32, 8), 0, stream>>>(V, Vtb);
    fused_bilinear<<<dim3(Bq / BM, Zq / BN), 512, 0, stream>>>(hdb, hpb, Utb, Vtb, out);
  } else {
    fallback_bilinear<<<dim3(Zq / 256, Bq / 8), 256, 0, stream>>>(hd, hp, U, V, out);
  }
  ln_rows<<<Bq, 256, 0, stream>>>(out, gamma, beta);
}